// Round 12
// baseline (368.282 us; speedup 1.0000x reference)
//
#include <hip/hip_runtime.h>
#include <hip/hip_fp16.h>
#include <cstdint>

// ---------------------------------------------------------------------------
// 3-layer GAT (PyG GATConv semantics) on MI355X.
//   CSR by dst -> per layer: fp16 MFMA GEMM (fp32 acc, fused fp32 alpha
//   epilogue, 64x64 wave tiles; layer-1 casts fp32 A in-staging)
//   -> lane-parallel edge-weight pass (w precomputed, coalesced [ET][4])
//   -> wave-per-dst aggregate, 16-edge batched index/weight prefetch
//      (16 independent feature gathers in flight per wave; the only
//       random-latency op in the loop is the feature gather itself).
// Feature path fp16; logits/softmax/accumulation fp32.
// ---------------------------------------------------------------------------

typedef _Float16 f16;
typedef _Float16 f16x8 __attribute__((ext_vector_type(8)));
typedef float f32x4 __attribute__((ext_vector_type(4)));

__global__ __launch_bounds__(256) void count_kernel(const int* __restrict__ ei,
                                                    int E, int N,
                                                    int* __restrict__ deg) {
  int g = blockIdx.x * 256 + threadIdx.x;
  if (g >= E + N) return;
  int dst = (g < E) ? ei[E + g] : (g - E);
  atomicAdd(&deg[dst], 1);
}

__global__ __launch_bounds__(256) void deg_block_reduce(const int* __restrict__ deg,
                                                        int* __restrict__ bsum, int N) {
  __shared__ int red[4];
  int b = blockIdx.x;
  int v = 0;
#pragma unroll
  for (int s = 0; s < 4; ++s) {
    int idx = b * 1024 + s * 256 + threadIdx.x;
    if (idx < N) v += deg[idx];
  }
  for (int off = 32; off; off >>= 1) v += __shfl_down(v, off);
  if ((threadIdx.x & 63) == 0) red[threadIdx.x >> 6] = v;
  __syncthreads();
  if (threadIdx.x == 0) bsum[b] = red[0] + red[1] + red[2] + red[3];
}

__global__ __launch_bounds__(1024) void small_scan(const int* __restrict__ bsum,
                                                   int* __restrict__ bpre, int NB) {
  __shared__ int buf[1024];
  int v = (threadIdx.x < NB) ? bsum[threadIdx.x] : 0;
  buf[threadIdx.x] = v;
  __syncthreads();
  for (int off = 1; off < 1024; off <<= 1) {
    int tv = (threadIdx.x >= off) ? buf[threadIdx.x - off] : 0;
    __syncthreads();
    buf[threadIdx.x] += tv;
    __syncthreads();
  }
  if (threadIdx.x < NB) bpre[threadIdx.x] = buf[threadIdx.x] - v;
}

__global__ __launch_bounds__(1024) void scan_final(const int* __restrict__ deg,
                                                   const int* __restrict__ bpre,
                                                   int* __restrict__ row_off,
                                                   int* __restrict__ cursor,
                                                   int N, int total) {
  __shared__ int buf[1024];
  int b = blockIdx.x;
  int i = b * 1024 + threadIdx.x;
  int v = (i < N) ? deg[i] : 0;
  buf[threadIdx.x] = v;
  __syncthreads();
  for (int off = 1; off < 1024; off <<= 1) {
    int tv = (threadIdx.x >= off) ? buf[threadIdx.x - off] : 0;
    __syncthreads();
    buf[threadIdx.x] += tv;
    __syncthreads();
  }
  if (i < N) {
    int ro = bpre[b] + buf[threadIdx.x] - v;
    row_off[i] = ro;
    cursor[i] = ro;
  }
  if (i == 0) row_off[N] = total;
}

__global__ __launch_bounds__(256) void scatter_kernel(const int* __restrict__ ei,
                                                      int E, int N,
                                                      int* __restrict__ cursor,
                                                      int* __restrict__ esrc,
                                                      int* __restrict__ edst) {
  int g = blockIdx.x * 256 + threadIdx.x;
  if (g >= E + N) return;
  int src, dst;
  if (g < E) { src = ei[g]; dst = ei[E + g]; }
  else       { src = g - E; dst = src; }
  int pos = atomicAdd(&cursor[dst], 1);
  esrc[pos] = src;
  edst[pos] = dst;
}

__global__ __launch_bounds__(256) void convert_wt(const float* __restrict__ W,
                                                  f16* __restrict__ Wt,
                                                  int K, int Ncol) {
  int t = blockIdx.x * 256 + threadIdx.x;
  if (t >= K * Ncol) return;
  int n = t % Ncol, k = t / Ncol;
  Wt[(size_t)n * K + k] = (f16)W[t];
}

// MFMA fp16 GEMM  T = A@B  with fused fp32 alpha epilogue; T written fp16.
// 256 thr (4 waves), tile 128 x BN, BK=32. BN=128: 2x2 waves, 64x64 wave
// tile (rf=4,cf=4). BN=64: 4x1 waves, 32x64 (rf=2,cf=4). ACAST: A is fp32.
template <int BN, bool ACAST>
__global__ __launch_bounds__(256) void mfma_gemm_alpha(
    const void* __restrict__ Ap_, const f16* __restrict__ Bt,
    f16* __restrict__ Tout,
    const float* __restrict__ avec_src, const float* __restrict__ avec_dst,
    float* __restrict__ asrc, float* __restrict__ adst,
    int M, int K, int Ncol) {
  constexpr int RF = (BN == 128) ? 4 : 2;
  __shared__ f16 As[128][40];
  __shared__ f16 Bs[BN][40];
  int tid = threadIdx.x;
  int wv = tid >> 6, lane = tid & 63;
  int lrow = lane & 15, lkb = lane >> 4;
  int row0 = blockIdx.x * 128, col0 = blockIdx.y * BN;
  int wro = (BN == 128) ? (wv >> 1) * 64 : wv * 32;
  int wco = (BN == 128) ? (wv & 1) * 64 : 0;
  int hg = (col0 + wco) >> 6;

  f32x4 acc[RF][4];
#pragma unroll
  for (int rf = 0; rf < RF; ++rf)
#pragma unroll
    for (int cf = 0; cf < 4; ++cf) acc[rf][cf] = (f32x4){0.f, 0.f, 0.f, 0.f};

  for (int kk = 0; kk < K; kk += 32) {
#pragma unroll
    for (int q = 0; q < 2; ++q) {
      int slot = tid + q * 256;
      int r = slot >> 2, ko = (slot & 3) << 3;
      int gr = min(row0 + r, M - 1);
      if (ACAST) {
        const float* Af = (const float*)Ap_ + (size_t)gr * K + kk + ko;
        float4 v0 = *reinterpret_cast<const float4*>(Af);
        float4 v1 = *reinterpret_cast<const float4*>(Af + 4);
        f16 o[8] = {(f16)v0.x, (f16)v0.y, (f16)v0.z, (f16)v0.w,
                    (f16)v1.x, (f16)v1.y, (f16)v1.z, (f16)v1.w};
        *reinterpret_cast<f16x8*>(&As[r][ko]) = *reinterpret_cast<f16x8*>(o);
      } else {
        *reinterpret_cast<f16x8*>(&As[r][ko]) =
            *reinterpret_cast<const f16x8*>((const f16*)Ap_ + (size_t)gr * K + kk + ko);
      }
    }
#pragma unroll
    for (int q = 0; q < BN / 64; ++q) {
      int slot = tid + q * 256;
      int c = slot >> 2, ko = (slot & 3) << 3;
      *reinterpret_cast<f16x8*>(&Bs[c][ko]) =
          *reinterpret_cast<const f16x8*>(&Bt[(size_t)(col0 + c) * K + kk + ko]);
    }
    __syncthreads();
    f16x8 af[RF], bf[4];
#pragma unroll
    for (int rf = 0; rf < RF; ++rf)
      af[rf] = *reinterpret_cast<f16x8*>(&As[wro + rf * 16 + lrow][lkb * 8]);
#pragma unroll
    for (int cf = 0; cf < 4; ++cf)
      bf[cf] = *reinterpret_cast<f16x8*>(&Bs[wco + cf * 16 + lrow][lkb * 8]);
#pragma unroll
    for (int rf = 0; rf < RF; ++rf)
#pragma unroll
      for (int cf = 0; cf < 4; ++cf)
        acc[rf][cf] = __builtin_amdgcn_mfma_f32_16x16x32_f16(af[rf], bf[cf],
                                                             acc[rf][cf], 0, 0, 0);
    __syncthreads();
  }

  int Hh = Ncol >> 6;
  float avs[4], avd[4];
#pragma unroll
  for (int cf = 0; cf < 4; ++cf) {
    avs[cf] = avec_src[hg * 64 + cf * 16 + lrow];
    avd[cf] = avec_dst[hg * 64 + cf * 16 + lrow];
  }

#pragma unroll
  for (int rf = 0; rf < RF; ++rf) {
#pragma unroll
    for (int r = 0; r < 4; ++r) {
      float ps = 0.f, pd = 0.f;
#pragma unroll
      for (int cf = 0; cf < 4; ++cf) {
        float v = acc[rf][cf][r];
        ps = fmaf(v, avs[cf], ps);
        pd = fmaf(v, avd[cf], pd);
      }
#pragma unroll
      for (int off = 1; off < 16; off <<= 1) {
        ps += __shfl_xor(ps, off);
        pd += __shfl_xor(pd, off);
      }
      int row = row0 + wro + rf * 16 + lkb * 4 + r;
      if (lrow == 0 && row < M) {
        asrc[row * Hh + hg] = ps;
        adst[row * Hh + hg] = pd;
      }
    }
#pragma unroll
    for (int r = 0; r < 4; ++r) {
      int row = row0 + wro + rf * 16 + lkb * 4 + r;
      if (row < M) {
#pragma unroll
        for (int cf = 0; cf < 4; ++cf)
          Tout[(size_t)row * Ncol + col0 + wco + cf * 16 + lrow] =
              (f16)acc[rf][cf][r];
      }
    }
  }
}

// Edge weights, layout [ET][4]: thread per (slot, head). Coalesced.
__global__ __launch_bounds__(256) void edge_weights_h4(
    const int* __restrict__ esrc, const int* __restrict__ edst,
    const float* __restrict__ asrc, const float* __restrict__ adst,
    float* __restrict__ w, int ET) {
  int t = blockIdx.x * 256 + threadIdx.x;
  if (t >= ET * 4) return;
  int j = t >> 2, h = t & 3;
  float e = asrc[esrc[j] * 4 + h] + adst[edst[j] * 4 + h];
  e = fmaxf(e, 0.2f * e);
  w[t] = __expf(e);
}

__global__ __launch_bounds__(256) void edge_weights_h1(
    const int* __restrict__ esrc, const int* __restrict__ edst,
    const float* __restrict__ asrc, const float* __restrict__ adst,
    float* __restrict__ w, int ET) {
  int j = blockIdx.x * 256 + threadIdx.x;
  if (j >= ET) return;
  float e = asrc[esrc[j]] + adst[edst[j]];
  e = fmaxf(e, 0.2f * e);
  w[j] = __expf(e);
}

// H=4 aggregate: ONE wave per dst (4/block). 16-edge batched prefetch:
// lanes 0-15 (per 16-group: ll) load esrc; lane (head*16 + i) holds w for
// (edge base+i, head); __shfl broadcasts -> 16 independent gathers in
// flight. Lane owns 4 channels (8B of the 512B row). No reductions.
template <bool ELU>
__global__ __launch_bounds__(256) void aggregate_h4(
    const f16* __restrict__ T16, const int* __restrict__ row_off,
    const int* __restrict__ esrc, const float* __restrict__ w,
    const float* __restrict__ bias, f16* __restrict__ outF, int N) {
  int wv = threadIdx.x >> 6, lane = threadIdx.x & 63;
  int dst = blockIdx.x * 4 + wv;
  if (dst >= N) return;
  int head = lane >> 4;
  int hsel = lane & 48;  // head*16
  int ll = lane & 15;
  int r0 = row_off[dst], r1 = row_off[dst + 1];
  const char* tbase = reinterpret_cast<const char*>(T16);
  uint loff = (uint)lane * 8;
  float den = 0.f, ax = 0.f, ay = 0.f, az = 0.f, aw = 0.f;
  for (int base = r0; base < r1; base += 16) {
    int jb = base + ll;
    int sv = 0;
    float wl = 0.f;
    if (jb < r1) {
      sv = esrc[jb];
      wl = w[(jb << 2) + head];
    }
    int cnt = min(16, r1 - base);
#pragma unroll 4
    for (int i = 0; i < cnt; ++i) {
      int sj = __shfl(sv, i);
      float wj = __shfl(wl, hsel + i);
      den += wj;
      uint2 raw = *reinterpret_cast<const uint2*>(tbase + (((uint)sj << 9) + loff));
      __half2 p0 = *reinterpret_cast<__half2*>(&raw.x);
      __half2 p1 = *reinterpret_cast<__half2*>(&raw.y);
      float2 f0 = __half22float2(p0);
      float2 f1 = __half22float2(p1);
      ax = fmaf(wj, f0.x, ax);
      ay = fmaf(wj, f0.y, ay);
      az = fmaf(wj, f1.x, az);
      aw = fmaf(wj, f1.y, aw);
    }
  }
  float rd = 1.f / den;
  float4 bv = *reinterpret_cast<const float4*>(&bias[lane << 2]);
  float vx = ax * rd + bv.x, vy = ay * rd + bv.y;
  float vz = az * rd + bv.z, vw = aw * rd + bv.w;
  if (ELU) {
    vx = vx > 0.f ? vx : expm1f(vx);
    vy = vy > 0.f ? vy : expm1f(vy);
    vz = vz > 0.f ? vz : expm1f(vz);
    vw = vw > 0.f ? vw : expm1f(vw);
  }
  f16 o[4] = {(f16)vx, (f16)vy, (f16)vz, (f16)vw};
  *reinterpret_cast<uint2*>(&outF[(size_t)dst * 256 + (lane << 2)]) =
      *reinterpret_cast<uint2*>(o);
}

// H=1 aggregate (layer 3): 16-lane group per dst (16 dst/block), 16-edge
// batched prefetch within the group. fp32 out.
__global__ __launch_bounds__(256) void aggregate_h1(
    const f16* __restrict__ T16, const int* __restrict__ row_off,
    const int* __restrict__ esrc, const float* __restrict__ w,
    const float* __restrict__ bias, float* __restrict__ out, int N) {
  int wv = threadIdx.x >> 6, lane = threadIdx.x & 63;
  int grp = lane >> 4, l = lane & 15;
  int gsel = lane & 48;
  int dst = blockIdx.x * 16 + wv * 4 + grp;
  if (dst >= N) return;
  int r0 = row_off[dst], r1 = row_off[dst + 1];
  const char* tbase = reinterpret_cast<const char*>(T16);
  uint loff = (uint)l * 8;
  float den = 0.f, ax = 0.f, ay = 0.f, az = 0.f, aw = 0.f;
  for (int base = r0; base < r1; base += 16) {
    int jb = base + l;
    int sv = 0;
    float wl = 0.f;
    if (jb < r1) {
      sv = esrc[jb];
      wl = w[jb];
    }
    int cnt = min(16, r1 - base);
#pragma unroll 4
    for (int i = 0; i < cnt; ++i) {
      int sj = __shfl(sv, gsel + i);
      float wj = __shfl(wl, gsel + i);
      den += wj;
      uint2 raw = *reinterpret_cast<const uint2*>(tbase + (((uint)sj << 7) + loff));
      __half2 p0 = *reinterpret_cast<__half2*>(&raw.x);
      __half2 p1 = *reinterpret_cast<__half2*>(&raw.y);
      float2 f0 = __half22float2(p0);
      float2 f1 = __half22float2(p1);
      ax = fmaf(wj, f0.x, ax);
      ay = fmaf(wj, f0.y, ay);
      az = fmaf(wj, f1.x, az);
      aw = fmaf(wj, f1.y, aw);
    }
  }
  float rd = 1.f / den;
  float4 v;
  v.x = ax * rd + bias[l * 4 + 0];
  v.y = ay * rd + bias[l * 4 + 1];
  v.z = az * rd + bias[l * 4 + 2];
  v.w = aw * rd + bias[l * 4 + 3];
  *reinterpret_cast<float4*>(&out[(size_t)dst * 64 + l * 4]) = v;
}

extern "C" void kernel_launch(void* const* d_in, const int* in_sizes, int n_in,
                              void* d_out, int out_size, void* d_ws, size_t ws_size,
                              hipStream_t stream) {
  const float* x   = (const float*)d_in[0];
  const int*   ei  = (const int*)d_in[1];
  const float* W1  = (const float*)d_in[2];
  const float* as1 = (const float*)d_in[3];
  const float* ad1 = (const float*)d_in[4];
  const float* b1  = (const float*)d_in[5];
  const float* W2  = (const float*)d_in[6];
  const float* as2 = (const float*)d_in[7];
  const float* ad2 = (const float*)d_in[8];
  const float* b2  = (const float*)d_in[9];
  const float* W3  = (const float*)d_in[10];
  const float* as3 = (const float*)d_in[11];
  const float* ad3 = (const float*)d_in[12];
  const float* b3  = (const float*)d_in[13];
  float* out = (float*)d_out;

  const int Fin = 128, H = 4, C = 64, HC = H * C;  // 256
  const int N = in_sizes[0] / Fin;
  const int E = in_sizes[1] / 2;
  const int ET = E + N;
  const int NB = (N + 1023) / 1024;

  // workspace layout (~70 MB)
  f16* T16   = (f16*)d_ws;                       // [N,256]
  f16* F16   = T16 + (size_t)N * HC;             // [N,256]
  f16* T16L3 = F16 + (size_t)N * HC;             // [N,64]
  f16* Wt1   = T16L3 + (size_t)N * C;            // [256,128]
  f16* Wt2   = Wt1 + HC * Fin;                   // [256,256]
  f16* Wt3   = Wt2 + HC * HC;                    // [64,256]
  float* asrc = (float*)(Wt3 + C * HC);          // [N,H]
  float* adst = asrc + (size_t)N * H;            // [N,H]
  float* wbuf = adst + (size_t)N * H;            // [ET*4]
  int* deg     = (int*)(wbuf + (size_t)ET * 4);
  int* row_off = deg + N;
  int* cursor  = row_off + (N + 1);
  int* bsum    = cursor + N;
  int* bpre    = bsum + NB;
  int* esrc    = bpre + NB;                      // [ET]
  int* edst    = esrc + ET;                      // [ET]

  // ---- CSR by destination ----
  hipMemsetAsync(deg, 0, N * sizeof(int), stream);
  count_kernel<<<(ET + 255) / 256, 256, 0, stream>>>(ei, E, N, deg);
  deg_block_reduce<<<NB, 256, 0, stream>>>(deg, bsum, N);
  small_scan<<<1, 1024, 0, stream>>>(bsum, bpre, NB);
  scan_final<<<NB, 1024, 0, stream>>>(deg, bpre, row_off, cursor, N, ET);
  scatter_kernel<<<(ET + 255) / 256, 256, 0, stream>>>(ei, E, N, cursor, esrc, edst);

  // ---- fp16 weight transposes ----
  convert_wt<<<(Fin * HC + 255) / 256, 256, 0, stream>>>(W1, Wt1, Fin, HC);
  convert_wt<<<(HC * HC + 255) / 256, 256, 0, stream>>>(W2, Wt2, HC, HC);
  convert_wt<<<(HC * C + 255) / 256, 256, 0, stream>>>(W3, Wt3, HC, C);

  int gx = (N + 127) / 128;
  int eb4 = (ET * 4 + 255) / 256, eb1 = (ET + 255) / 256;
  int ab4 = (N + 3) / 4;
  int ab1 = (N + 15) / 16;

  // ---- Layer 1: 128 -> 4x64 (concat) + ELU ----
  mfma_gemm_alpha<128, true><<<dim3(gx, 2), 256, 0, stream>>>(
      x, Wt1, T16, as1, ad1, asrc, adst, N, Fin, HC);
  edge_weights_h4<<<eb4, 256, 0, stream>>>(esrc, edst, asrc, adst, wbuf, ET);
  aggregate_h4<true><<<ab4, 256, 0, stream>>>(T16, row_off, esrc, wbuf, b1, F16, N);

  // ---- Layer 2: 256 -> 4x64 (concat) + ELU ----
  mfma_gemm_alpha<128, false><<<dim3(gx, 2), 256, 0, stream>>>(
      F16, Wt2, T16, as2, ad2, asrc, adst, N, HC, HC);
  edge_weights_h4<<<eb4, 256, 0, stream>>>(esrc, edst, asrc, adst, wbuf, ET);
  aggregate_h4<true><<<ab4, 256, 0, stream>>>(T16, row_off, esrc, wbuf, b2, F16, N);

  // ---- Layer 3: 256 -> 1x64 ----
  mfma_gemm_alpha<64, false><<<dim3(gx, 1), 256, 0, stream>>>(
      F16, Wt3, T16L3, as3, ad3, asrc, adst, N, HC, C);
  edge_weights_h1<<<eb1, 256, 0, stream>>>(esrc, edst, asrc, adst, wbuf, ET);
  aggregate_h1<<<ab1, 256, 0, stream>>>(T16L3, row_off, esrc, wbuf, b3, out, N);
}

// Round 13
// 358.129 us; speedup vs baseline: 1.0283x; 1.0283x over previous
//
#include <hip/hip_runtime.h>
#include <hip/hip_fp16.h>
#include <cstdint>

// ---------------------------------------------------------------------------
// 3-layer GAT (PyG GATConv semantics) on MI355X.
//   CSR by dst -> per layer: fp16 MFMA GEMM (fp32 acc, fused fp32 alpha
//   epilogue, 64x64 wave tiles; layer-1 casts fp32 A in-staging)
//   -> lane-parallel edge-weight pass (w precomputed, coalesced [ET][4])
//   -> aggregate: 2 dsts per wave, fixed-8 masked batches -> 16 independent
//      512B row-gathers in flight per wave (gather-latency-bound regime).
// Feature path fp16; logits/softmax/accumulation fp32.
// ---------------------------------------------------------------------------

typedef _Float16 f16;
typedef _Float16 f16x8 __attribute__((ext_vector_type(8)));
typedef float f32x4 __attribute__((ext_vector_type(4)));

__global__ __launch_bounds__(256) void count_kernel(const int* __restrict__ ei,
                                                    int E, int N,
                                                    int* __restrict__ deg) {
  int g = blockIdx.x * 256 + threadIdx.x;
  if (g >= E + N) return;
  int dst = (g < E) ? ei[E + g] : (g - E);
  atomicAdd(&deg[dst], 1);
}

__global__ __launch_bounds__(256) void deg_block_reduce(const int* __restrict__ deg,
                                                        int* __restrict__ bsum, int N) {
  __shared__ int red[4];
  int b = blockIdx.x;
  int v = 0;
#pragma unroll
  for (int s = 0; s < 4; ++s) {
    int idx = b * 1024 + s * 256 + threadIdx.x;
    if (idx < N) v += deg[idx];
  }
  for (int off = 32; off; off >>= 1) v += __shfl_down(v, off);
  if ((threadIdx.x & 63) == 0) red[threadIdx.x >> 6] = v;
  __syncthreads();
  if (threadIdx.x == 0) bsum[b] = red[0] + red[1] + red[2] + red[3];
}

__global__ __launch_bounds__(1024) void small_scan(const int* __restrict__ bsum,
                                                   int* __restrict__ bpre, int NB) {
  __shared__ int buf[1024];
  int v = (threadIdx.x < NB) ? bsum[threadIdx.x] : 0;
  buf[threadIdx.x] = v;
  __syncthreads();
  for (int off = 1; off < 1024; off <<= 1) {
    int tv = (threadIdx.x >= off) ? buf[threadIdx.x - off] : 0;
    __syncthreads();
    buf[threadIdx.x] += tv;
    __syncthreads();
  }
  if (threadIdx.x < NB) bpre[threadIdx.x] = buf[threadIdx.x] - v;
}

__global__ __launch_bounds__(1024) void scan_final(const int* __restrict__ deg,
                                                   const int* __restrict__ bpre,
                                                   int* __restrict__ row_off,
                                                   int* __restrict__ cursor,
                                                   int N, int total) {
  __shared__ int buf[1024];
  int b = blockIdx.x;
  int i = b * 1024 + threadIdx.x;
  int v = (i < N) ? deg[i] : 0;
  buf[threadIdx.x] = v;
  __syncthreads();
  for (int off = 1; off < 1024; off <<= 1) {
    int tv = (threadIdx.x >= off) ? buf[threadIdx.x - off] : 0;
    __syncthreads();
    buf[threadIdx.x] += tv;
    __syncthreads();
  }
  if (i < N) {
    int ro = bpre[b] + buf[threadIdx.x] - v;
    row_off[i] = ro;
    cursor[i] = ro;
  }
  if (i == 0) row_off[N] = total;
}

__global__ __launch_bounds__(256) void scatter_kernel(const int* __restrict__ ei,
                                                      int E, int N,
                                                      int* __restrict__ cursor,
                                                      int* __restrict__ esrc,
                                                      int* __restrict__ edst) {
  int g = blockIdx.x * 256 + threadIdx.x;
  if (g >= E + N) return;
  int src, dst;
  if (g < E) { src = ei[g]; dst = ei[E + g]; }
  else       { src = g - E; dst = src; }
  int pos = atomicAdd(&cursor[dst], 1);
  esrc[pos] = src;
  edst[pos] = dst;
}

// All three weight transposes in one dispatch.
__global__ __launch_bounds__(256) void convert_wt_all(
    const float* __restrict__ W1, const float* __restrict__ W2,
    const float* __restrict__ W3, f16* __restrict__ Wt1, f16* __restrict__ Wt2,
    f16* __restrict__ Wt3, int n1, int n2, int n3, int N1, int N2, int N3,
    int K1, int K2, int K3) {
  int t = blockIdx.x * 256 + threadIdx.x;
  if (t < n1) {
    int n = t % N1, k = t / N1;
    Wt1[(size_t)n * K1 + k] = (f16)W1[t];
    return;
  }
  t -= n1;
  if (t < n2) {
    int n = t % N2, k = t / N2;
    Wt2[(size_t)n * K2 + k] = (f16)W2[t];
    return;
  }
  t -= n2;
  if (t < n3) {
    int n = t % N3, k = t / N3;
    Wt3[(size_t)n * K3 + k] = (f16)W3[t];
  }
}

// MFMA fp16 GEMM  T = A@B  with fused fp32 alpha epilogue; T written fp16.
// 256 thr (4 waves), tile 128 x BN, BK=32. BN=128: 2x2 waves, 64x64 wave
// tile (rf=4,cf=4). BN=64: 4x1 waves, 32x64 (rf=2,cf=4). ACAST: A is fp32.
template <int BN, bool ACAST>
__global__ __launch_bounds__(256) void mfma_gemm_alpha(
    const void* __restrict__ Ap_, const f16* __restrict__ Bt,
    f16* __restrict__ Tout,
    const float* __restrict__ avec_src, const float* __restrict__ avec_dst,
    float* __restrict__ asrc, float* __restrict__ adst,
    int M, int K, int Ncol) {
  constexpr int RF = (BN == 128) ? 4 : 2;
  __shared__ f16 As[128][40];
  __shared__ f16 Bs[BN][40];
  int tid = threadIdx.x;
  int wv = tid >> 6, lane = tid & 63;
  int lrow = lane & 15, lkb = lane >> 4;
  int row0 = blockIdx.x * 128, col0 = blockIdx.y * BN;
  int wro = (BN == 128) ? (wv >> 1) * 64 : wv * 32;
  int wco = (BN == 128) ? (wv & 1) * 64 : 0;
  int hg = (col0 + wco) >> 6;

  f32x4 acc[RF][4];
#pragma unroll
  for (int rf = 0; rf < RF; ++rf)
#pragma unroll
    for (int cf = 0; cf < 4; ++cf) acc[rf][cf] = (f32x4){0.f, 0.f, 0.f, 0.f};

  for (int kk = 0; kk < K; kk += 32) {
#pragma unroll
    for (int q = 0; q < 2; ++q) {
      int slot = tid + q * 256;
      int r = slot >> 2, ko = (slot & 3) << 3;
      int gr = min(row0 + r, M - 1);
      if (ACAST) {
        const float* Af = (const float*)Ap_ + (size_t)gr * K + kk + ko;
        float4 v0 = *reinterpret_cast<const float4*>(Af);
        float4 v1 = *reinterpret_cast<const float4*>(Af + 4);
        f16 o[8] = {(f16)v0.x, (f16)v0.y, (f16)v0.z, (f16)v0.w,
                    (f16)v1.x, (f16)v1.y, (f16)v1.z, (f16)v1.w};
        *reinterpret_cast<f16x8*>(&As[r][ko]) = *reinterpret_cast<f16x8*>(o);
      } else {
        *reinterpret_cast<f16x8*>(&As[r][ko]) =
            *reinterpret_cast<const f16x8*>((const f16*)Ap_ + (size_t)gr * K + kk + ko);
      }
    }
#pragma unroll
    for (int q = 0; q < BN / 64; ++q) {
      int slot = tid + q * 256;
      int c = slot >> 2, ko = (slot & 3) << 3;
      *reinterpret_cast<f16x8*>(&Bs[c][ko]) =
          *reinterpret_cast<const f16x8*>(&Bt[(size_t)(col0 + c) * K + kk + ko]);
    }
    __syncthreads();
    f16x8 af[RF], bf[4];
#pragma unroll
    for (int rf = 0; rf < RF; ++rf)
      af[rf] = *reinterpret_cast<f16x8*>(&As[wro + rf * 16 + lrow][lkb * 8]);
#pragma unroll
    for (int cf = 0; cf < 4; ++cf)
      bf[cf] = *reinterpret_cast<f16x8*>(&Bs[wco + cf * 16 + lrow][lkb * 8]);
#pragma unroll
    for (int rf = 0; rf < RF; ++rf)
#pragma unroll
      for (int cf = 0; cf < 4; ++cf)
        acc[rf][cf] = __builtin_amdgcn_mfma_f32_16x16x32_f16(af[rf], bf[cf],
                                                             acc[rf][cf], 0, 0, 0);
    __syncthreads();
  }

  int Hh = Ncol >> 6;
  float avs[4], avd[4];
#pragma unroll
  for (int cf = 0; cf < 4; ++cf) {
    avs[cf] = avec_src[hg * 64 + cf * 16 + lrow];
    avd[cf] = avec_dst[hg * 64 + cf * 16 + lrow];
  }

#pragma unroll
  for (int rf = 0; rf < RF; ++rf) {
#pragma unroll
    for (int r = 0; r < 4; ++r) {
      float ps = 0.f, pd = 0.f;
#pragma unroll
      for (int cf = 0; cf < 4; ++cf) {
        float v = acc[rf][cf][r];
        ps = fmaf(v, avs[cf], ps);
        pd = fmaf(v, avd[cf], pd);
      }
#pragma unroll
      for (int off = 1; off < 16; off <<= 1) {
        ps += __shfl_xor(ps, off);
        pd += __shfl_xor(pd, off);
      }
      int row = row0 + wro + rf * 16 + lkb * 4 + r;
      if (lrow == 0 && row < M) {
        asrc[row * Hh + hg] = ps;
        adst[row * Hh + hg] = pd;
      }
    }
#pragma unroll
    for (int r = 0; r < 4; ++r) {
      int row = row0 + wro + rf * 16 + lkb * 4 + r;
      if (row < M) {
#pragma unroll
        for (int cf = 0; cf < 4; ++cf)
          Tout[(size_t)row * Ncol + col0 + wco + cf * 16 + lrow] =
              (f16)acc[rf][cf][r];
      }
    }
  }
}

// Edge weights, layout [ET][4]: thread per (slot, head). Coalesced.
__global__ __launch_bounds__(256) void edge_weights_h4(
    const int* __restrict__ esrc, const int* __restrict__ edst,
    const float* __restrict__ asrc, const float* __restrict__ adst,
    float* __restrict__ w, int ET) {
  int t = blockIdx.x * 256 + threadIdx.x;
  if (t >= ET * 4) return;
  int j = t >> 2, h = t & 3;
  float e = asrc[esrc[j] * 4 + h] + adst[edst[j] * 4 + h];
  e = fmaxf(e, 0.2f * e);
  w[t] = __expf(e);
}

__global__ __launch_bounds__(256) void edge_weights_h1(
    const int* __restrict__ esrc, const int* __restrict__ edst,
    const float* __restrict__ asrc, const float* __restrict__ adst,
    float* __restrict__ w, int ET) {
  int j = blockIdx.x * 256 + threadIdx.x;
  if (j >= ET) return;
  float e = asrc[esrc[j]] + adst[edst[j]];
  e = fmaxf(e, 0.2f * e);
  w[j] = __expf(e);
}

// H=4 aggregate: TWO dsts per wave (8/block). Per batch: lanes 0-31 stage
// 8 edges of dst0 (lane = e*4+h loads esrc/w), lanes 32-63 stage dst1;
// fixed-unroll inner loop issues 16 independent 512B row-gathers (8/dst).
// Lane owns 4 channels (head = lane>>4) for BOTH dsts. No reductions.
template <bool ELU>
__global__ __launch_bounds__(256) void aggregate_h4(
    const f16* __restrict__ T16, const int* __restrict__ row_off,
    const int* __restrict__ esrc, const float* __restrict__ w,
    const float* __restrict__ bias, f16* __restrict__ outF, int N) {
  int wv = threadIdx.x >> 6, lane = threadIdx.x & 63;
  int dst0 = blockIdx.x * 8 + wv * 2;
  if (dst0 >= N) return;
  bool has1 = (dst0 + 1 < N);
  int dst1 = has1 ? dst0 + 1 : dst0;
  int head = lane >> 4;
  int ds = lane >> 5, e4 = (lane >> 2) & 7, hh = lane & 3;
  int r0a = row_off[dst0], r1a = row_off[dst0 + 1];
  int r1b = row_off[dst1 + 1];
  int r0b = row_off[dst1];
  int sr0 = ds ? r0b : r0a, sr1 = ds ? r1b : r1a;
  const char* tbase = reinterpret_cast<const char*>(T16);
  uint loff = (uint)lane * 8;
  float den0 = 0.f, den1 = 0.f;
  float a0x = 0.f, a0y = 0.f, a0z = 0.f, a0w = 0.f;
  float a1x = 0.f, a1y = 0.f, a1z = 0.f, a1w = 0.f;
  int nb = max(r1a - r0a, r1b - r0b);
  for (int base = 0; base < nb; base += 8) {
    int jb = sr0 + base + e4;
    int sv;
    float wl;
    if (jb < sr1) {
      sv = esrc[jb];
      wl = w[(jb << 2) + hh];
    } else {
      sv = esrc[sr1 - 1];  // valid (deg >= 1 via self-loop)
      wl = 0.f;
    }
#pragma unroll
    for (int i = 0; i < 8; ++i) {
      int sj0 = __shfl(sv, i * 4);
      float wj0 = __shfl(wl, i * 4 + head);
      int sj1 = __shfl(sv, 32 + i * 4);
      float wj1 = __shfl(wl, 32 + i * 4 + head);
      uint2 raw0 = *reinterpret_cast<const uint2*>(tbase + (((uint)sj0 << 9) + loff));
      uint2 raw1 = *reinterpret_cast<const uint2*>(tbase + (((uint)sj1 << 9) + loff));
      den0 += wj0;
      den1 += wj1;
      __half2 q0 = *reinterpret_cast<__half2*>(&raw0.x);
      __half2 q1 = *reinterpret_cast<__half2*>(&raw0.y);
      float2 f0 = __half22float2(q0);
      float2 f1 = __half22float2(q1);
      a0x = fmaf(wj0, f0.x, a0x);
      a0y = fmaf(wj0, f0.y, a0y);
      a0z = fmaf(wj0, f1.x, a0z);
      a0w = fmaf(wj0, f1.y, a0w);
      __half2 q2 = *reinterpret_cast<__half2*>(&raw1.x);
      __half2 q3 = *reinterpret_cast<__half2*>(&raw1.y);
      float2 f2 = __half22float2(q2);
      float2 f3 = __half22float2(q3);
      a1x = fmaf(wj1, f2.x, a1x);
      a1y = fmaf(wj1, f2.y, a1y);
      a1z = fmaf(wj1, f3.x, a1z);
      a1w = fmaf(wj1, f3.y, a1w);
    }
  }
  float4 bv = *reinterpret_cast<const float4*>(&bias[lane << 2]);
  {
    float rd = 1.f / den0;
    float vx = a0x * rd + bv.x, vy = a0y * rd + bv.y;
    float vz = a0z * rd + bv.z, vw = a0w * rd + bv.w;
    if (ELU) {
      vx = vx > 0.f ? vx : expm1f(vx);
      vy = vy > 0.f ? vy : expm1f(vy);
      vz = vz > 0.f ? vz : expm1f(vz);
      vw = vw > 0.f ? vw : expm1f(vw);
    }
    f16 o[4] = {(f16)vx, (f16)vy, (f16)vz, (f16)vw};
    *reinterpret_cast<uint2*>(&outF[(size_t)dst0 * 256 + (lane << 2)]) =
        *reinterpret_cast<uint2*>(o);
  }
  if (has1) {
    float rd = 1.f / den1;
    float vx = a1x * rd + bv.x, vy = a1y * rd + bv.y;
    float vz = a1z * rd + bv.z, vw = a1w * rd + bv.w;
    if (ELU) {
      vx = vx > 0.f ? vx : expm1f(vx);
      vy = vy > 0.f ? vy : expm1f(vy);
      vz = vz > 0.f ? vz : expm1f(vz);
      vw = vw > 0.f ? vw : expm1f(vw);
    }
    f16 o[4] = {(f16)vx, (f16)vy, (f16)vz, (f16)vw};
    *reinterpret_cast<uint2*>(&outF[(size_t)dst1 * 256 + (lane << 2)]) =
        *reinterpret_cast<uint2*>(o);
  }
}

// H=1 aggregate (layer 3): 16-lane group per dst (16 dst/block), fixed-8
// masked batches. fp32 out.
__global__ __launch_bounds__(256) void aggregate_h1(
    const f16* __restrict__ T16, const int* __restrict__ row_off,
    const int* __restrict__ esrc, const float* __restrict__ w,
    const float* __restrict__ bias, float* __restrict__ out, int N) {
  int wv = threadIdx.x >> 6, lane = threadIdx.x & 63;
  int grp = lane >> 4, l = lane & 15;
  int gsel = lane & 48;
  int dst = blockIdx.x * 16 + wv * 4 + grp;
  if (dst >= N) return;
  int r0 = row_off[dst], r1 = row_off[dst + 1];
  const char* tbase = reinterpret_cast<const char*>(T16);
  uint loff = (uint)l * 8;
  float den = 0.f, ax = 0.f, ay = 0.f, az = 0.f, aw = 0.f;
  for (int base = r0; base < r1; base += 8) {
    int jb = base + (l & 7);
    int sv = 0;
    float wl = 0.f;
    if (jb < r1) {
      sv = esrc[jb];
      wl = w[jb];
    }
#pragma unroll
    for (int i = 0; i < 8; ++i) {
      int sj = __shfl(sv, gsel + i);
      float wj = __shfl(wl, gsel + i);
      den += wj;
      uint2 raw = *reinterpret_cast<const uint2*>(tbase + (((uint)sj << 7) + loff));
      __half2 p0 = *reinterpret_cast<__half2*>(&raw.x);
      __half2 p1 = *reinterpret_cast<__half2*>(&raw.y);
      float2 f0 = __half22float2(p0);
      float2 f1 = __half22float2(p1);
      ax = fmaf(wj, f0.x, ax);
      ay = fmaf(wj, f0.y, ay);
      az = fmaf(wj, f1.x, az);
      aw = fmaf(wj, f1.y, aw);
    }
  }
  float rd = 1.f / den;
  float4 v;
  v.x = ax * rd + bias[l * 4 + 0];
  v.y = ay * rd + bias[l * 4 + 1];
  v.z = az * rd + bias[l * 4 + 2];
  v.w = aw * rd + bias[l * 4 + 3];
  *reinterpret_cast<float4*>(&out[(size_t)dst * 64 + l * 4]) = v;
}

extern "C" void kernel_launch(void* const* d_in, const int* in_sizes, int n_in,
                              void* d_out, int out_size, void* d_ws, size_t ws_size,
                              hipStream_t stream) {
  const float* x   = (const float*)d_in[0];
  const int*   ei  = (const int*)d_in[1];
  const float* W1  = (const float*)d_in[2];
  const float* as1 = (const float*)d_in[3];
  const float* ad1 = (const float*)d_in[4];
  const float* b1  = (const float*)d_in[5];
  const float* W2  = (const float*)d_in[6];
  const float* as2 = (const float*)d_in[7];
  const float* ad2 = (const float*)d_in[8];
  const float* b2  = (const float*)d_in[9];
  const float* W3  = (const float*)d_in[10];
  const float* as3 = (const float*)d_in[11];
  const float* ad3 = (const float*)d_in[12];
  const float* b3  = (const float*)d_in[13];
  float* out = (float*)d_out;

  const int Fin = 128, H = 4, C = 64, HC = H * C;  // 256
  const int N = in_sizes[0] / Fin;
  const int E = in_sizes[1] / 2;
  const int ET = E + N;
  const int NB = (N + 1023) / 1024;

  // workspace layout (~70 MB)
  f16* T16   = (f16*)d_ws;                       // [N,256]
  f16* F16   = T16 + (size_t)N * HC;             // [N,256]
  f16* T16L3 = F16 + (size_t)N * HC;             // [N,64]
  f16* Wt1   = T16L3 + (size_t)N * C;            // [256,128]
  f16* Wt2   = Wt1 + HC * Fin;                   // [256,256]
  f16* Wt3   = Wt2 + HC * HC;                    // [64,256]
  float* asrc = (float*)(Wt3 + C * HC);          // [N,H]
  float* adst = asrc + (size_t)N * H;            // [N,H]
  float* wbuf = adst + (size_t)N * H;            // [ET*4]
  int* deg     = (int*)(wbuf + (size_t)ET * 4);
  int* row_off = deg + N;
  int* cursor  = row_off + (N + 1);
  int* bsum    = cursor + N;
  int* bpre    = bsum + NB;
  int* esrc    = bpre + NB;                      // [ET]
  int* edst    = esrc + ET;                      // [ET]

  // ---- CSR by destination ----
  hipMemsetAsync(deg, 0, N * sizeof(int), stream);
  count_kernel<<<(ET + 255) / 256, 256, 0, stream>>>(ei, E, N, deg);
  deg_block_reduce<<<NB, 256, 0, stream>>>(deg, bsum, N);
  small_scan<<<1, 1024, 0, stream>>>(bsum, bpre, NB);
  scan_final<<<NB, 1024, 0, stream>>>(deg, bpre, row_off, cursor, N, ET);
  scatter_kernel<<<(ET + 255) / 256, 256, 0, stream>>>(ei, E, N, cursor, esrc, edst);

  // ---- fp16 weight transposes (single dispatch) ----
  int n1 = Fin * HC, n2 = HC * HC, n3 = HC * C;
  convert_wt_all<<<(n1 + n2 + n3 + 255) / 256, 256, 0, stream>>>(
      W1, W2, W3, Wt1, Wt2, Wt3, n1, n2, n3, HC, HC, C, Fin, HC, HC);

  int gx = (N + 127) / 128;
  int eb4 = (ET * 4 + 255) / 256, eb1 = (ET + 255) / 256;
  int ab4 = (N + 7) / 8;
  int ab1 = (N + 15) / 16;

  // ---- Layer 1: 128 -> 4x64 (concat) + ELU ----
  mfma_gemm_alpha<128, true><<<dim3(gx, 2), 256, 0, stream>>>(
      x, Wt1, T16, as1, ad1, asrc, adst, N, Fin, HC);
  edge_weights_h4<<<eb4, 256, 0, stream>>>(esrc, edst, asrc, adst, wbuf, ET);
  aggregate_h4<true><<<ab4, 256, 0, stream>>>(T16, row_off, esrc, wbuf, b1, F16, N);

  // ---- Layer 2: 256 -> 4x64 (concat) + ELU ----
  mfma_gemm_alpha<128, false><<<dim3(gx, 2), 256, 0, stream>>>(
      F16, Wt2, T16, as2, ad2, asrc, adst, N, HC, HC);
  edge_weights_h4<<<eb4, 256, 0, stream>>>(esrc, edst, asrc, adst, wbuf, ET);
  aggregate_h4<true><<<ab4, 256, 0, stream>>>(T16, row_off, esrc, wbuf, b2, F16, N);

  // ---- Layer 3: 256 -> 1x64 ----
  mfma_gemm_alpha<64, false><<<dim3(gx, 1), 256, 0, stream>>>(
      F16, Wt3, T16L3, as3, ad3, asrc, adst, N, HC, C);
  edge_weights_h1<<<eb1, 256, 0, stream>>>(esrc, edst, asrc, adst, wbuf, ET);
  aggregate_h1<<<ab1, 256, 0, stream>>>(T16L3, row_off, esrc, wbuf, b3, out, N);
}

// Round 14
// 324.468 us; speedup vs baseline: 1.1350x; 1.1037x over previous
//
#include <hip/hip_runtime.h>
#include <hip/hip_fp16.h>
#include <cstdint>

// ---------------------------------------------------------------------------
// 3-layer GAT (PyG GATConv semantics) on MI355X.
//   CSR by dst -> per layer: fp16 MFMA GEMM (fp32 acc, fused fp32 alpha
//   epilogue; layer-1 casts fp32 A in-staging) -> lane-parallel edge weights
//   ([ET][4] coalesced) -> wave-per-dst aggregate, fixed-8 masked edge
//   batches (8 independent 512B row-gathers in flight; gather-latency-bound).
// Component provenance: aggregate = round-10 (61us measured optimum);
// GEMM + merged converts = round-13. Feature path fp16; logits fp32.
// ---------------------------------------------------------------------------

typedef _Float16 f16;
typedef _Float16 f16x8 __attribute__((ext_vector_type(8)));
typedef float f32x4 __attribute__((ext_vector_type(4)));

__global__ __launch_bounds__(256) void count_kernel(const int* __restrict__ ei,
                                                    int E, int N,
                                                    int* __restrict__ deg) {
  int g = blockIdx.x * 256 + threadIdx.x;
  if (g >= E + N) return;
  int dst = (g < E) ? ei[E + g] : (g - E);
  atomicAdd(&deg[dst], 1);
}

__global__ __launch_bounds__(256) void deg_block_reduce(const int* __restrict__ deg,
                                                        int* __restrict__ bsum, int N) {
  __shared__ int red[4];
  int b = blockIdx.x;
  int v = 0;
#pragma unroll
  for (int s = 0; s < 4; ++s) {
    int idx = b * 1024 + s * 256 + threadIdx.x;
    if (idx < N) v += deg[idx];
  }
  for (int off = 32; off; off >>= 1) v += __shfl_down(v, off);
  if ((threadIdx.x & 63) == 0) red[threadIdx.x >> 6] = v;
  __syncthreads();
  if (threadIdx.x == 0) bsum[b] = red[0] + red[1] + red[2] + red[3];
}

__global__ __launch_bounds__(1024) void small_scan(const int* __restrict__ bsum,
                                                   int* __restrict__ bpre, int NB) {
  __shared__ int buf[1024];
  int v = (threadIdx.x < NB) ? bsum[threadIdx.x] : 0;
  buf[threadIdx.x] = v;
  __syncthreads();
  for (int off = 1; off < 1024; off <<= 1) {
    int tv = (threadIdx.x >= off) ? buf[threadIdx.x - off] : 0;
    __syncthreads();
    buf[threadIdx.x] += tv;
    __syncthreads();
  }
  if (threadIdx.x < NB) bpre[threadIdx.x] = buf[threadIdx.x] - v;
}

__global__ __launch_bounds__(1024) void scan_final(const int* __restrict__ deg,
                                                   const int* __restrict__ bpre,
                                                   int* __restrict__ row_off,
                                                   int* __restrict__ cursor,
                                                   int N, int total) {
  __shared__ int buf[1024];
  int b = blockIdx.x;
  int i = b * 1024 + threadIdx.x;
  int v = (i < N) ? deg[i] : 0;
  buf[threadIdx.x] = v;
  __syncthreads();
  for (int off = 1; off < 1024; off <<= 1) {
    int tv = (threadIdx.x >= off) ? buf[threadIdx.x - off] : 0;
    __syncthreads();
    buf[threadIdx.x] += tv;
    __syncthreads();
  }
  if (i < N) {
    int ro = bpre[b] + buf[threadIdx.x] - v;
    row_off[i] = ro;
    cursor[i] = ro;
  }
  if (i == 0) row_off[N] = total;
}

__global__ __launch_bounds__(256) void scatter_kernel(const int* __restrict__ ei,
                                                      int E, int N,
                                                      int* __restrict__ cursor,
                                                      int* __restrict__ esrc,
                                                      int* __restrict__ edst) {
  int g = blockIdx.x * 256 + threadIdx.x;
  if (g >= E + N) return;
  int src, dst;
  if (g < E) { src = ei[g]; dst = ei[E + g]; }
  else       { src = g - E; dst = src; }
  int pos = atomicAdd(&cursor[dst], 1);
  esrc[pos] = src;
  edst[pos] = dst;
}

// All three weight transposes in one dispatch.
__global__ __launch_bounds__(256) void convert_wt_all(
    const float* __restrict__ W1, const float* __restrict__ W2,
    const float* __restrict__ W3, f16* __restrict__ Wt1, f16* __restrict__ Wt2,
    f16* __restrict__ Wt3, int n1, int n2, int n3, int N1, int N2, int N3,
    int K1, int K2, int K3) {
  int t = blockIdx.x * 256 + threadIdx.x;
  if (t < n1) {
    int n = t % N1, k = t / N1;
    Wt1[(size_t)n * K1 + k] = (f16)W1[t];
    return;
  }
  t -= n1;
  if (t < n2) {
    int n = t % N2, k = t / N2;
    Wt2[(size_t)n * K2 + k] = (f16)W2[t];
    return;
  }
  t -= n2;
  if (t < n3) {
    int n = t % N3, k = t / N3;
    Wt3[(size_t)n * K3 + k] = (f16)W3[t];
  }
}

// MFMA fp16 GEMM  T = A@B  with fused fp32 alpha epilogue; T written fp16.
// 256 thr (4 waves), tile 128 x BN, BK=32. BN=128: 2x2 waves, 64x64 wave
// tile (rf=4,cf=4). BN=64: 4x1 waves, 32x64 (rf=2,cf=4). ACAST: A is fp32.
template <int BN, bool ACAST>
__global__ __launch_bounds__(256) void mfma_gemm_alpha(
    const void* __restrict__ Ap_, const f16* __restrict__ Bt,
    f16* __restrict__ Tout,
    const float* __restrict__ avec_src, const float* __restrict__ avec_dst,
    float* __restrict__ asrc, float* __restrict__ adst,
    int M, int K, int Ncol) {
  constexpr int RF = (BN == 128) ? 4 : 2;
  __shared__ f16 As[128][40];
  __shared__ f16 Bs[BN][40];
  int tid = threadIdx.x;
  int wv = tid >> 6, lane = tid & 63;
  int lrow = lane & 15, lkb = lane >> 4;
  int row0 = blockIdx.x * 128, col0 = blockIdx.y * BN;
  int wro = (BN == 128) ? (wv >> 1) * 64 : wv * 32;
  int wco = (BN == 128) ? (wv & 1) * 64 : 0;
  int hg = (col0 + wco) >> 6;

  f32x4 acc[RF][4];
#pragma unroll
  for (int rf = 0; rf < RF; ++rf)
#pragma unroll
    for (int cf = 0; cf < 4; ++cf) acc[rf][cf] = (f32x4){0.f, 0.f, 0.f, 0.f};

  for (int kk = 0; kk < K; kk += 32) {
#pragma unroll
    for (int q = 0; q < 2; ++q) {
      int slot = tid + q * 256;
      int r = slot >> 2, ko = (slot & 3) << 3;
      int gr = min(row0 + r, M - 1);
      if (ACAST) {
        const float* Af = (const float*)Ap_ + (size_t)gr * K + kk + ko;
        float4 v0 = *reinterpret_cast<const float4*>(Af);
        float4 v1 = *reinterpret_cast<const float4*>(Af + 4);
        f16 o[8] = {(f16)v0.x, (f16)v0.y, (f16)v0.z, (f16)v0.w,
                    (f16)v1.x, (f16)v1.y, (f16)v1.z, (f16)v1.w};
        *reinterpret_cast<f16x8*>(&As[r][ko]) = *reinterpret_cast<f16x8*>(o);
      } else {
        *reinterpret_cast<f16x8*>(&As[r][ko]) =
            *reinterpret_cast<const f16x8*>((const f16*)Ap_ + (size_t)gr * K + kk + ko);
      }
    }
#pragma unroll
    for (int q = 0; q < BN / 64; ++q) {
      int slot = tid + q * 256;
      int c = slot >> 2, ko = (slot & 3) << 3;
      *reinterpret_cast<f16x8*>(&Bs[c][ko]) =
          *reinterpret_cast<const f16x8*>(&Bt[(size_t)(col0 + c) * K + kk + ko]);
    }
    __syncthreads();
    f16x8 af[RF], bf[4];
#pragma unroll
    for (int rf = 0; rf < RF; ++rf)
      af[rf] = *reinterpret_cast<f16x8*>(&As[wro + rf * 16 + lrow][lkb * 8]);
#pragma unroll
    for (int cf = 0; cf < 4; ++cf)
      bf[cf] = *reinterpret_cast<f16x8*>(&Bs[wco + cf * 16 + lrow][lkb * 8]);
#pragma unroll
    for (int rf = 0; rf < RF; ++rf)
#pragma unroll
      for (int cf = 0; cf < 4; ++cf)
        acc[rf][cf] = __builtin_amdgcn_mfma_f32_16x16x32_f16(af[rf], bf[cf],
                                                             acc[rf][cf], 0, 0, 0);
    __syncthreads();
  }

  int Hh = Ncol >> 6;
  float avs[4], avd[4];
#pragma unroll
  for (int cf = 0; cf < 4; ++cf) {
    avs[cf] = avec_src[hg * 64 + cf * 16 + lrow];
    avd[cf] = avec_dst[hg * 64 + cf * 16 + lrow];
  }

#pragma unroll
  for (int rf = 0; rf < RF; ++rf) {
#pragma unroll
    for (int r = 0; r < 4; ++r) {
      float ps = 0.f, pd = 0.f;
#pragma unroll
      for (int cf = 0; cf < 4; ++cf) {
        float v = acc[rf][cf][r];
        ps = fmaf(v, avs[cf], ps);
        pd = fmaf(v, avd[cf], pd);
      }
#pragma unroll
      for (int off = 1; off < 16; off <<= 1) {
        ps += __shfl_xor(ps, off);
        pd += __shfl_xor(pd, off);
      }
      int row = row0 + wro + rf * 16 + lkb * 4 + r;
      if (lrow == 0 && row < M) {
        asrc[row * Hh + hg] = ps;
        adst[row * Hh + hg] = pd;
      }
    }
#pragma unroll
    for (int r = 0; r < 4; ++r) {
      int row = row0 + wro + rf * 16 + lkb * 4 + r;
      if (row < M) {
#pragma unroll
        for (int cf = 0; cf < 4; ++cf)
          Tout[(size_t)row * Ncol + col0 + wco + cf * 16 + lrow] =
              (f16)acc[rf][cf][r];
      }
    }
  }
}

// Edge weights, layout [ET][4]: thread per (slot, head). Coalesced.
__global__ __launch_bounds__(256) void edge_weights_h4(
    const int* __restrict__ esrc, const int* __restrict__ edst,
    const float* __restrict__ asrc, const float* __restrict__ adst,
    float* __restrict__ w, int ET) {
  int t = blockIdx.x * 256 + threadIdx.x;
  if (t >= ET * 4) return;
  int j = t >> 2, h = t & 3;
  float e = asrc[esrc[j] * 4 + h] + adst[edst[j] * 4 + h];
  e = fmaxf(e, 0.2f * e);
  w[t] = __expf(e);
}

__global__ __launch_bounds__(256) void edge_weights_h1(
    const int* __restrict__ esrc, const int* __restrict__ edst,
    const float* __restrict__ asrc, const float* __restrict__ adst,
    float* __restrict__ w, int ET) {
  int j = blockIdx.x * 256 + threadIdx.x;
  if (j >= ET) return;
  float e = asrc[esrc[j]] + adst[edst[j]];
  e = fmaxf(e, 0.2f * e);
  w[j] = __expf(e);
}

// H=4 aggregate (round-10 optimum): ONE wave per dst (4 waves/block).
// Batched 8-edge prefetch: lanes 0-7 load 8 edges' esrc; lane (head*16+i<8)
// loads w for (edge i, its head); __shfl broadcasts -> 8 independent
// gathers in flight. Lane owns 4 channels (8B of the 512B row). No
// reductions: every lane sees all edges.
template <bool ELU>
__global__ __launch_bounds__(256) void aggregate_h4(
    const f16* __restrict__ T16, const int* __restrict__ row_off,
    const int* __restrict__ esrc, const float* __restrict__ w,
    const float* __restrict__ bias, f16* __restrict__ outF, int N) {
  int wv = threadIdx.x >> 6, lane = threadIdx.x & 63;
  int dst = blockIdx.x * 4 + wv;
  if (dst >= N) return;
  int head = lane >> 4;
  int hsel = lane & 48;  // head*16
  int r0 = row_off[dst], r1 = row_off[dst + 1];
  const char* tbase = reinterpret_cast<const char*>(T16);
  uint loff = (uint)lane * 8;
  float den = 0.f, ax = 0.f, ay = 0.f, az = 0.f, aw = 0.f;
  for (int base = r0; base < r1; base += 8) {
    int jb = base + (lane & 7);
    int sv = 0;
    float wl = 0.f;
    if (jb < r1) {
      sv = esrc[jb];
      wl = w[(jb << 2) + head];
    }
#pragma unroll
    for (int i = 0; i < 8; ++i) {
      int sj = __shfl(sv, i);
      float wj = __shfl(wl, hsel + i);
      den += wj;
      uint2 raw = *reinterpret_cast<const uint2*>(tbase + (((uint)sj << 9) + loff));
      __half2 p0 = *reinterpret_cast<__half2*>(&raw.x);
      __half2 p1 = *reinterpret_cast<__half2*>(&raw.y);
      float2 f0 = __half22float2(p0);
      float2 f1 = __half22float2(p1);
      ax = fmaf(wj, f0.x, ax);
      ay = fmaf(wj, f0.y, ay);
      az = fmaf(wj, f1.x, az);
      aw = fmaf(wj, f1.y, aw);
    }
  }
  float rd = 1.f / den;
  float4 bv = *reinterpret_cast<const float4*>(&bias[lane << 2]);
  float vx = ax * rd + bv.x, vy = ay * rd + bv.y;
  float vz = az * rd + bv.z, vw = aw * rd + bv.w;
  if (ELU) {
    vx = vx > 0.f ? vx : expm1f(vx);
    vy = vy > 0.f ? vy : expm1f(vy);
    vz = vz > 0.f ? vz : expm1f(vz);
    vw = vw > 0.f ? vw : expm1f(vw);
  }
  f16 o[4] = {(f16)vx, (f16)vy, (f16)vz, (f16)vw};
  *reinterpret_cast<uint2*>(&outF[(size_t)dst * 256 + (lane << 2)]) =
      *reinterpret_cast<uint2*>(o);
}

// H=1 aggregate (round-10 form): 16-lane group per dst (16 dst/block),
// fixed-8 masked batched prefetch within the group. fp32 out.
__global__ __launch_bounds__(256) void aggregate_h1(
    const f16* __restrict__ T16, const int* __restrict__ row_off,
    const int* __restrict__ esrc, const float* __restrict__ w,
    const float* __restrict__ bias, float* __restrict__ out, int N) {
  int wv = threadIdx.x >> 6, lane = threadIdx.x & 63;
  int grp = lane >> 4, l = lane & 15;
  int gsel = lane & 48;
  int dst = blockIdx.x * 16 + wv * 4 + grp;
  if (dst >= N) return;
  int r0 = row_off[dst], r1 = row_off[dst + 1];
  const char* tbase = reinterpret_cast<const char*>(T16);
  uint loff = (uint)l * 8;
  float den = 0.f, ax = 0.f, ay = 0.f, az = 0.f, aw = 0.f;
  for (int base = r0; base < r1; base += 8) {
    int jb = base + (l & 7);
    int sv = 0;
    float wl = 0.f;
    if (jb < r1) {
      sv = esrc[jb];
      wl = w[jb];
    }
#pragma unroll
    for (int i = 0; i < 8; ++i) {
      int sj = __shfl(sv, gsel + i);
      float wj = __shfl(wl, gsel + i);
      den += wj;
      uint2 raw = *reinterpret_cast<const uint2*>(tbase + (((uint)sj << 7) + loff));
      __half2 p0 = *reinterpret_cast<__half2*>(&raw.x);
      __half2 p1 = *reinterpret_cast<__half2*>(&raw.y);
      float2 f0 = __half22float2(p0);
      float2 f1 = __half22float2(p1);
      ax = fmaf(wj, f0.x, ax);
      ay = fmaf(wj, f0.y, ay);
      az = fmaf(wj, f1.x, az);
      aw = fmaf(wj, f1.y, aw);
    }
  }
  float rd = 1.f / den;
  float4 v;
  v.x = ax * rd + bias[l * 4 + 0];
  v.y = ay * rd + bias[l * 4 + 1];
  v.z = az * rd + bias[l * 4 + 2];
  v.w = aw * rd + bias[l * 4 + 3];
  *reinterpret_cast<float4*>(&out[(size_t)dst * 64 + l * 4]) = v;
}

extern "C" void kernel_launch(void* const* d_in, const int* in_sizes, int n_in,
                              void* d_out, int out_size, void* d_ws, size_t ws_size,
                              hipStream_t stream) {
  const float* x   = (const float*)d_in[0];
  const int*   ei  = (const int*)d_in[1];
  const float* W1  = (const float*)d_in[2];
  const float* as1 = (const float*)d_in[3];
  const float* ad1 = (const float*)d_in[4];
  const float* b1  = (const float*)d_in[5];
  const float* W2  = (const float*)d_in[6];
  const float* as2 = (const float*)d_in[7];
  const float* ad2 = (const float*)d_in[8];
  const float* b2  = (const float*)d_in[9];
  const float* W3  = (const float*)d_in[10];
  const float* as3 = (const float*)d_in[11];
  const float* ad3 = (const float*)d_in[12];
  const float* b3  = (const float*)d_in[13];
  float* out = (float*)d_out;

  const int Fin = 128, H = 4, C = 64, HC = H * C;  // 256
  const int N = in_sizes[0] / Fin;
  const int E = in_sizes[1] / 2;
  const int ET = E + N;
  const int NB = (N + 1023) / 1024;

  // workspace layout (~70 MB)
  f16* T16   = (f16*)d_ws;                       // [N,256]
  f16* F16   = T16 + (size_t)N * HC;             // [N,256]
  f16* T16L3 = F16 + (size_t)N * HC;             // [N,64]
  f16* Wt1   = T16L3 + (size_t)N * C;            // [256,128]
  f16* Wt2   = Wt1 + HC * Fin;                   // [256,256]
  f16* Wt3   = Wt2 + HC * HC;                    // [64,256]
  float* asrc = (float*)(Wt3 + C * HC);          // [N,H]
  float* adst = asrc + (size_t)N * H;            // [N,H]
  float* wbuf = adst + (size_t)N * H;            // [ET*4]
  int* deg     = (int*)(wbuf + (size_t)ET * 4);
  int* row_off = deg + N;
  int* cursor  = row_off + (N + 1);
  int* bsum    = cursor + N;
  int* bpre    = bsum + NB;
  int* esrc    = bpre + NB;                      // [ET]
  int* edst    = esrc + ET;                      // [ET]

  // ---- CSR by destination ----
  hipMemsetAsync(deg, 0, N * sizeof(int), stream);
  count_kernel<<<(ET + 255) / 256, 256, 0, stream>>>(ei, E, N, deg);
  deg_block_reduce<<<NB, 256, 0, stream>>>(deg, bsum, N);
  small_scan<<<1, 1024, 0, stream>>>(bsum, bpre, NB);
  scan_final<<<NB, 1024, 0, stream>>>(deg, bpre, row_off, cursor, N, ET);
  scatter_kernel<<<(ET + 255) / 256, 256, 0, stream>>>(ei, E, N, cursor, esrc, edst);

  // ---- fp16 weight transposes (single dispatch) ----
  int n1 = Fin * HC, n2 = HC * HC, n3 = HC * C;
  convert_wt_all<<<(n1 + n2 + n3 + 255) / 256, 256, 0, stream>>>(
      W1, W2, W3, Wt1, Wt2, Wt3, n1, n2, n3, HC, HC, C, Fin, HC, HC);

  int gx = (N + 127) / 128;
  int eb4 = (ET * 4 + 255) / 256, eb1 = (ET + 255) / 256;
  int ab4 = (N + 3) / 4;
  int ab1 = (N + 15) / 16;

  // ---- Layer 1: 128 -> 4x64 (concat) + ELU ----
  mfma_gemm_alpha<128, true><<<dim3(gx, 2), 256, 0, stream>>>(
      x, Wt1, T16, as1, ad1, asrc, adst, N, Fin, HC);
  edge_weights_h4<<<eb4, 256, 0, stream>>>(esrc, edst, asrc, adst, wbuf, ET);
  aggregate_h4<true><<<ab4, 256, 0, stream>>>(T16, row_off, esrc, wbuf, b1, F16, N);

  // ---- Layer 2: 256 -> 4x64 (concat) + ELU ----
  mfma_gemm_alpha<128, false><<<dim3(gx, 2), 256, 0, stream>>>(
      F16, Wt2, T16, as2, ad2, asrc, adst, N, HC, HC);
  edge_weights_h4<<<eb4, 256, 0, stream>>>(esrc, edst, asrc, adst, wbuf, ET);
  aggregate_h4<true><<<ab4, 256, 0, stream>>>(T16, row_off, esrc, wbuf, b2, F16, N);

  // ---- Layer 3: 256 -> 1x64 ----
  mfma_gemm_alpha<64, false><<<dim3(gx, 1), 256, 0, stream>>>(
      F16, Wt3, T16L3, as3, ad3, asrc, adst, N, HC, C);
  edge_weights_h1<<<eb1, 256, 0, stream>>>(esrc, edst, asrc, adst, wbuf, ET);
  aggregate_h1<<<ab1, 256, 0, stream>>>(T16L3, row_off, esrc, wbuf, b3, out, N);
}